// Round 9
// baseline (168.384 us; speedup 1.0000x reference)
//
#include <hip/hip_runtime.h>
#include <stdint.h>

#define N_PROP 100000
#define N_LAB  256
#define NW     8                      // 256 bits / 32
#define NCHUNK 391                    // ceil(100000/256) blocks in k_masks
#define N_PAD  (NCHUNK * 256)         // 100096 padded proposals
#define NROWS  (NCHUNK * 4)           // 1564 rows of 64 proposals
#define NROWP  1568                   // padded stride for transposed rowOR
#define RANK_BLOCKS 128

// d_ws byte offsets
#define OFF_MASKS 0
#define OFF_ROWOR (N_PAD * NW * 4)                     // 3,203,072
#define OFF_TPCNT (OFF_ROWOR + NROWS * NW * 4)         // +50,048
#define OFF_KEYS  (OFF_TPCNT + 16)
#define OFF_HIST  (OFF_KEYS + N_LAB * 8)
#define OFF_DONE  (OFF_HIST + 260 * 4)

// first pending label from 4 x u64 pending words (-1 if none)
#define FIRST_PEND(j_i, w0, w1, w2, w3)         \
  {                                             \
    j_i = -1;                                   \
    if (w3) j_i = 192 + (__ffsll(w3) - 1);      \
    if (w2) j_i = 128 + (__ffsll(w2) - 1);      \
    if (w1) j_i = 64 + (__ffsll(w1) - 1);       \
    if (w0) j_i = (__ffsll(w0) - 1);            \
  }

// ---------------------------------------------------------------------------
// Kernel 1: per-proposal 256-bit IoU>0.5 masks + per-ROW(64) ORs. Block 0
// zeroes hist + done ticket (ws is not re-poisoned between replays).
// Arithmetic bit-identical to the reference (IEEE div, same op order).
// ---------------------------------------------------------------------------
__global__ __launch_bounds__(256) void k_masks(
    const float* __restrict__ prop, const float* __restrict__ lab,
    uint32_t* __restrict__ masks, uint32_t* __restrict__ rowOR,
    int* __restrict__ hist, int* __restrict__ done_ctr) {
  __shared__ float4 s_lab[N_LAB];     // (bmin, bmax, blen, 0)
  __shared__ uint32_t s_orr[4][NW];   // per-64-row ORs
  const int t = threadIdx.x;
  if (t < 32) s_orr[t >> 3][t & 7] = 0u;
  {
    const float bmn = lab[2 * t], bmx = lab[2 * t + 1];
    s_lab[t] = make_float4(bmn, bmx, bmx - bmn, 0.0f);
  }
  if (blockIdx.x == 0) {
    hist[t] = 0;
    if (t == 0) { hist[N_LAB] = 0; done_ctr[0] = 0; }
  }
  __syncthreads();

  const int i = blockIdx.x * 256 + t;
  uint32_t m[NW];
#pragma unroll
  for (int w = 0; w < NW; ++w) m[w] = 0u;

  if (i < N_PROP) {
    const float ps = prop[3 * i + 1], pe = prop[3 * i + 2];
    const float amin = ps / 25.0f;
    const float amax = pe / 25.0f;
    const float alen = amax - amin;
#pragma unroll 4
    for (int j = 0; j < N_LAB; ++j) {
      const float4 L = s_lab[j];
      float inter = fminf(amax, L.y) - fmaxf(amin, L.x);
      inter = fmaxf(inter, 0.0f);
      const float uni = (alen - inter) + L.z;
      const float iou = inter / uni;           // IEEE div, as reference
      if (iou > 0.5f) m[j >> 5] |= (1u << (j & 31));
    }
  }

  uint4* mp = reinterpret_cast<uint4*>(&masks[(size_t)i * NW]);
  mp[0] = make_uint4(m[0], m[1], m[2], m[3]);
  mp[1] = make_uint4(m[4], m[5], m[6], m[7]);

  uint32_t any = 0u;
#pragma unroll
  for (int w = 0; w < NW; ++w) any |= m[w];
  if (any) {
    const int rr = t >> 6;
#pragma unroll
    for (int w = 0; w < NW; ++w)
      if (m[w]) atomicOr(&s_orr[rr][w], m[w]);
  }
  __syncthreads();
  if (t < 32) rowOR[blockIdx.x * 32 + t] = s_orr[t >> 3][t & 7];
}

// ---------------------------------------------------------------------------
// Kernel 2: exact sequential greedy scan (wave 0) + TP key sort (all 256).
// Claim semantics proven vs reference (absmax 0.0 in R4/R6/R7/R8): proposals
// evaluated exactly once in ascending index order; a proposal claims the
// first label of (mask & ~detected), if any, then stops. detected only
// grows => clean rows stay clean (skip-ahead sound), queued flagged rows
// that became clean exit on the drain's first (empty) ballot.
//
// R9 structure: serial unit = 64-proposal ROW; all row flags in LDS
// (transposed, conflict-free); 4-slot software pipeline with STATIC register
// roles (no queue rotation -> no forced vmcnt waits): drain slot k, then
// find next flagged row (monotone cursor) and issue its 2x16B mask load into
// slot k's registers -- ~3 drain rounds for the load to land.
// ---------------------------------------------------------------------------
#define FLAGROW(RR, FV)                                                     \
  FV = (s_rT[0 * NROWP + (RR)] & ~D0) | (s_rT[1 * NROWP + (RR)] & ~D1) |    \
       (s_rT[2 * NROWP + (RR)] & ~D2) | (s_rT[3 * NROWP + (RR)] & ~D3) |    \
       (s_rT[4 * NROWP + (RR)] & ~D4) | (s_rT[5 * NROWP + (RR)] & ~D5) |    \
       (s_rT[6 * NROWP + (RR)] & ~D6) | (s_rT[7 * NROWP + (RR)] & ~D7);

#define FINDROW(RES)                                                        \
  {                                                                         \
    RES = -1;                                                               \
    while (cursor < NROWS) {                                                \
      const int rr_ = cursor + lane;                                        \
      uint32_t f_ = 0u;                                                     \
      if (rr_ < NROWS) { FLAGROW(rr_, f_); }                                \
      const unsigned long long bal_ = __ballot(f_ != 0u);                   \
      if (bal_ != 0ull) {                                                   \
        RES = cursor + (__ffsll(bal_) - 1);                                 \
        cursor = RES + 1;                                                   \
        break;                                                              \
      }                                                                     \
      cursor += 64;                                                         \
    }                                                                       \
  }

// row RID, lane's proposal = RID*64+lane; masks fully written to N_PAD rows
// by k_masks; max word index = (1563*64+63)*8+8 = 800,768 = N_PAD*NW: bounds OK
#define LOADROW(RID, MA, MB)                                                \
  {                                                                         \
    const uint4* qm_ = reinterpret_cast<const uint4*>(                      \
        &masks[(size_t)((RID) * 64 + lane) * NW]);                          \
    MA = qm_[0];                                                            \
    MB = qm_[1];                                                            \
  }

#define DRAIN64(BASE, VA, VB)                                               \
  {                                                                         \
    unsigned long long w0 = ((unsigned long long)(VA.y & ~D1) << 32) |      \
                            (unsigned long long)(uint32_t)(VA.x & ~D0);     \
    unsigned long long w1 = ((unsigned long long)(VA.w & ~D3) << 32) |      \
                            (unsigned long long)(uint32_t)(VA.z & ~D2);     \
    unsigned long long w2 = ((unsigned long long)(VB.y & ~D5) << 32) |      \
                            (unsigned long long)(uint32_t)(VB.x & ~D4);     \
    unsigned long long w3 = ((unsigned long long)(VB.w & ~D7) << 32) |      \
                            (unsigned long long)(uint32_t)(VB.z & ~D6);     \
    int j_i;                                                                \
    FIRST_PEND(j_i, w0, w1, w2, w3);                                        \
    while (true) {                                                          \
      const unsigned long long rbal = __ballot(j_i >= 0);                   \
      if (rbal == 0ull) break;                                              \
      const int l_ = __ffsll(rbal) - 1;      /* min pending lane */         \
      const int j_ = __builtin_amdgcn_readlane(j_i, l_);  /* its claim */   \
      const uint32_t bit_ = 1u << (j_ & 31);                                \
      const int q5_ = j_ >> 5;                                              \
      D0 |= (q5_ == 0) ? bit_ : 0u;  D1 |= (q5_ == 1) ? bit_ : 0u;          \
      D2 |= (q5_ == 2) ? bit_ : 0u;  D3 |= (q5_ == 3) ? bit_ : 0u;          \
      D4 |= (q5_ == 4) ? bit_ : 0u;  D5 |= (q5_ == 5) ? bit_ : 0u;          \
      D6 |= (q5_ == 6) ? bit_ : 0u;  D7 |= (q5_ == 7) ? bit_ : 0u;          \
      if (lane == 0 && T < N_LAB) s_tpi[T] = (BASE) + l_;                   \
      ++T;                                                                  \
      if (lane == l_) { w0 = 0; w1 = 0; w2 = 0; w3 = 0; } /* consumed */    \
      const unsigned long long bm_ = 1ull << (j_ & 63);                     \
      const int q6_ = j_ >> 6;                                              \
      w0 &= (q6_ == 0) ? ~bm_ : ~0ull;  w1 &= (q6_ == 1) ? ~bm_ : ~0ull;    \
      w2 &= (q6_ == 2) ? ~bm_ : ~0ull;  w3 &= (q6_ == 3) ? ~bm_ : ~0ull;    \
      FIRST_PEND(j_i, w0, w1, w2, w3);                                      \
    }                                                                       \
  }

#define STEP(RID, MA, MB)                                                   \
  if (RID >= 0) {                                                           \
    DRAIN64((RID) * 64, MA, MB);  /* empty ballot = cheap re-validation */  \
    FINDROW(RID);                                                           \
    if (RID >= 0) { LOADROW(RID, MA, MB); }                                 \
  }

__global__ __launch_bounds__(256) void k_scansort(
    const uint32_t* __restrict__ masks, const uint32_t* __restrict__ rowOR,
    const float* __restrict__ prop,
    unsigned long long* __restrict__ keys, int* __restrict__ tp_cnt) {
  __shared__ uint32_t s_rT[NW * NROWP];        // transposed row flags, ~50 KB
  __shared__ int s_tpi[N_LAB];
  __shared__ int s_T;
  __shared__ unsigned long long s_key[N_LAB];
  __shared__ unsigned long long s_srt[N_LAB];
  const int t = threadIdx.x;

  // stage rowOR transposed (f = row*8+w -> s_rT[w][row]); coalesced reads
#pragma unroll 4
  for (int f = t; f < NROWS * NW; f += 256)
    s_rT[(f & 7) * NROWP + (f >> 3)] = rowOR[f];
  __syncthreads();

  if (t < 64) {
    const int lane = t;
    uint32_t D0 = 0, D1 = 0, D2 = 0, D3 = 0, D4 = 0, D5 = 0, D6 = 0, D7 = 0;
    int T = 0;
    int cursor = 0;
    int r0, r1, r2, r3;
    uint4 m0a = make_uint4(0,0,0,0), m0b = m0a, m1a = m0a, m1b = m0a;
    uint4 m2a = m0a, m2b = m0a, m3a = m0a, m3b = m0a;

    FINDROW(r0); if (r0 >= 0) { LOADROW(r0, m0a, m0b); }
    FINDROW(r1); if (r1 >= 0) { LOADROW(r1, m1a, m1b); }
    FINDROW(r2); if (r2 >= 0) { LOADROW(r2, m2a, m2b); }
    FINDROW(r3); if (r3 >= 0) { LOADROW(r3, m3a, m3b); }
    while (r0 >= 0 || r1 >= 0 || r2 >= 0 || r3 >= 0) {
      STEP(r0, m0a, m0b);
      STEP(r1, m1a, m1b);
      STEP(r2, m2a, m2b);
      STEP(r3, m3a, m3b);
    }
    if (lane == 0) s_T = (T < N_LAB) ? T : N_LAB;
  }
  __syncthreads();

  // ---- TP key build + counting sort (all 256 threads; proven) ----
  // key = conf_bits<<32 | (0xFFFFFFFF - idx): exactly the reference's stable
  // argsort(-conf) priority (conf >= 0; ties -> lower idx first).
  const int T = s_T;
  unsigned long long k = ~0ull;
  if (t < T) {
    const int it = s_tpi[t];
    const unsigned cb = __float_as_uint(prop[3 * it]);
    k = ((unsigned long long)cb << 32) |
        (unsigned long long)(0xFFFFFFFFu - (unsigned)it);
  }
  s_key[t] = k;
  s_srt[t] = ~0ull;
  __syncthreads();
  int pos = 0;
  for (int s = 0; s < N_LAB; ++s) pos += (s_key[s] < k) ? 1 : 0;
  if (t < T) s_srt[pos] = k;                   // real keys distinct
  __syncthreads();
  keys[t] = s_srt[t];
  if (t == 0) tp_cnt[0] = T;
}

// ---------------------------------------------------------------------------
// Kernel 3: rank histogram (grid-stride, 128 blocks) + last-block AP fan-in.
// p_i = #{sorted TP keys < key_i} via exact lower_bound in [0,256] (9-step
// guarded search, proven). Ticket fan-in: last block to finish does the
// exact integer suffix-scan and the bit-exact fp AP loop.
// AP = (1/256) * sum_{i: p_i >= 2} max_{j>=i} (j / p_j), descending order;
// rank-1 term excluded (reference's x[:-1] quirk).
// ---------------------------------------------------------------------------
__global__ __launch_bounds__(256) void k_rankap(
    const float* __restrict__ prop, const unsigned long long* __restrict__ keys,
    const int* __restrict__ tp_cnt, int* __restrict__ hist,
    int* __restrict__ done_ctr, float* __restrict__ out) {
  __shared__ unsigned long long s_key[N_LAB];
  __shared__ int s_hist[N_LAB + 1];
  __shared__ int s_last;
  __shared__ int s_a[N_LAB + 1];
  __shared__ int s_b[N_LAB + 1];
  __shared__ int s_p[N_LAB];
  const int t = threadIdx.x;
  s_key[t] = keys[t];
  s_hist[t] = 0;
  if (t == 0) s_hist[N_LAB] = 0;
  __syncthreads();

  for (int i = blockIdx.x * 256 + t; i < N_PROP; i += RANK_BLOCKS * 256) {
    const unsigned cb = __float_as_uint(prop[3 * i]);
    const unsigned long long k =
        ((unsigned long long)cb << 32) |
        (unsigned long long)(0xFFFFFFFFu - (unsigned)i);
    int p = 0;
#pragma unroll
    for (int s = 256; s > 0; s >>= 1) {
      const int cand = p + s;
      if (cand <= N_LAB && s_key[cand - 1] < k) p = cand;
    }
    atomicAdd(&s_hist[p], 1);
  }
  __syncthreads();
  if (s_hist[t] != 0) atomicAdd(&hist[t], s_hist[t]);
  if (t == 0 && s_hist[N_LAB] != 0) atomicAdd(&hist[N_LAB], s_hist[N_LAB]);

  __threadfence();                              // release partial sums
  if (t == 0)
    s_last = (atomicAdd(done_ctr, 1) == RANK_BLOCKS - 1) ? 1 : 0;
  __syncthreads();
  if (!s_last) return;
  __threadfence();                              // acquire all partials

  int T = tp_cnt[0];
  T = (T < 0) ? 0 : ((T > N_LAB) ? N_LAB : T);
  s_a[t] = atomicAdd(&hist[t], 0);              // coherent read
  if (t == 0) s_a[N_LAB] = atomicAdd(&hist[N_LAB], 0);
  __syncthreads();
  int* src = s_a;
  int* dst = s_b;
#pragma unroll
  for (int s = 1; s <= N_LAB; s <<= 1) {        // exact int suffix scan
    const int v = src[t] + ((t + s <= N_LAB) ? src[t + s] : 0);
    const int v256 = (t == 0) ? src[N_LAB] : 0;
    __syncthreads();
    dst[t] = v;
    if (t == 0) dst[N_LAB] = v256;
    __syncthreads();
    int* tmp = src; src = dst; dst = tmp;
  }
  if (t < T) s_p[(T - 1) - t] = 1 + src[t + 1]; // ranks ascending
  __syncthreads();
  if (t == 0) {
    float m = 0.0f, sum = 0.0f;
    for (int i = T - 1; i >= 0; --i) {
      const float prec = (float)(i + 1) / (float)s_p[i];  // IEEE div, as ref
      m = fmaxf(m, prec);
      if (s_p[i] >= 2) sum += m * 0.00390625f;  // * (1/256), exact
    }
    out[0] = sum;
  }
}

extern "C" void kernel_launch(void* const* d_in, const int* in_sizes, int n_in,
                              void* d_out, int out_size, void* d_ws,
                              size_t ws_size, hipStream_t stream) {
  (void)in_sizes; (void)n_in; (void)out_size; (void)ws_size;
  const float* prop = (const float*)d_in[0];
  const float* lab  = (const float*)d_in[1];
  uint8_t* ws = (uint8_t*)d_ws;
  uint32_t* masks  = (uint32_t*)(ws + OFF_MASKS);
  uint32_t* rowOR  = (uint32_t*)(ws + OFF_ROWOR);
  int*      tp_cnt = (int*)(ws + OFF_TPCNT);
  unsigned long long* keys = (unsigned long long*)(ws + OFF_KEYS);
  int*      hist   = (int*)(ws + OFF_HIST);
  int*      done   = (int*)(ws + OFF_DONE);
  float*    out    = (float*)d_out;

  k_masks   <<<dim3(NCHUNK),      dim3(256), 0, stream>>>(prop, lab, masks, rowOR, hist, done);
  k_scansort<<<dim3(1),           dim3(256), 0, stream>>>(masks, rowOR, prop, keys, tp_cnt);
  k_rankap  <<<dim3(RANK_BLOCKS), dim3(256), 0, stream>>>(prop, keys, tp_cnt, hist, done, out);
}